// Round 11
// baseline (160.278 us; speedup 1.0000x reference)
//
#include <hip/hip_runtime.h>
#include <math.h>

constexpr int DIM   = 128;
constexpr int KC    = 1024;
constexpr int NROWS = 65536;                 // 16384*512/128
constexpr int XEL   = NROWS * DIM;           // 8388608

// output layout (floats)
constexpr int OUT_Z     = 0;
constexpr int OUT_DIFF  = XEL;               // 8388608
constexpr int OUT_CODES = XEL + 1;           // 8388609
constexpr int OUT_PPL   = XEL + 1 + NROWS;   // 8454145

// ws layout (4-byte units)
constexpr int WS_IDX  = 0;                   // int[NROWS]
constexpr int WS_FLAG = NROWS;               // int[NROWS]
constexpr int WS_CNT  = 2 * NROWS;           // int   (zeroed by k_prep)
constexpr int WS_DONE = WS_CNT + 1;          // u32   (zeroed by k_prep)
constexpr int WS_HIST = WS_DONE + 1;         // u32[KC] (zeroed by k_prep)
constexpr int WS_HN   = WS_HIST + KC;        // float[KC]
constexpr int WS_PART = WS_HN + KC;          // float[2048] diff partials
constexpr int WS_HN64 = WS_PART + 2048;      // double[KC] (2048 words, 8B-aligned)
constexpr int WS_EF   = WS_HN64 + 2 * KC;    // _Float16[KC*DIM] = 65536 words
constexpr int WS_ET   = WS_EF + (KC * DIM / 2); // float[DIM*KC] transposed = 131072 words

constexpr int NB_OUT  = 2048;                // k_out output blocks
constexpr int NB_HIST = 64;                  // k_out histogram blocks

// single-pass f16 score error std ~5e-3; 0.06 = >10 sigma pairwise margin
constexpr float GAP_THR = 0.06f;

typedef _Float16 f16x8 __attribute__((ext_vector_type(8)));
typedef _Float16 f16x4 __attribute__((ext_vector_type(4)));
typedef float f32x4 __attribute__((ext_vector_type(4)));

// ---- emb -> f16 + transposed fp32 + fp64 half-norms; zero counters/hist ----
__global__ __launch_bounds__(256) void k_prep(
        const float* __restrict__ emb, _Float16* __restrict__ ef,
        float* __restrict__ embT, float* __restrict__ hn,
        double* __restrict__ hn64, unsigned* __restrict__ zbase) {
    __shared__ float ldsT[DIM][9];            // 8 codes transposed, +1 pad col
    const int tid = threadIdx.x;
    if (blockIdx.x == 0)
        for (int i = tid; i < 2 + KC; i += 256) zbase[i] = 0u;   // CNT, DONE, HIST
    const int cc   = tid >> 5;                // 0..7 code within block
    const int code = blockIdx.x * 8 + cc;
    const int jq   = tid & 31;                // float4 index
    float4 v = *(const float4*)(emb + (size_t)code * DIM + jq * 4);
    f16x4 h = { (_Float16)v.x, (_Float16)v.y, (_Float16)v.z, (_Float16)v.w };
    *(f16x4*)(ef + (size_t)code * DIM + jq * 4) = h;
    ldsT[jq * 4 + 0][cc] = v.x;
    ldsT[jq * 4 + 1][cc] = v.y;
    ldsT[jq * 4 + 2][cc] = v.z;
    ldsT[jq * 4 + 3][cc] = v.w;
    double s = (double)v.x * v.x + (double)v.y * v.y
             + (double)v.z * v.z + (double)v.w * v.w;
    #pragma unroll
    for (int m = 1; m < 32; m <<= 1) s += __shfl_xor(s, m);
    if (jq == 0) {
        hn[code]   = (float)(0.5 * s);
        hn64[code] = 0.5 * s;
    }
    __syncthreads();
    #pragma unroll
    for (int i = 0; i < 4; ++i) {
        int idx = i * 256 + tid;
        int j = idx >> 3, c = idx & 7;
        embT[(size_t)j * KC + blockIdx.x * 8 + c] = ldsT[j][c];
    }
}

// ---- main: 2 waves x (64 rows x 512 codes), codebook split across waves.
// B loaded L2->VGPR with explicit register double-buffer; no per-tile sync;
// one end-of-kernel LDS merge of the two code-halves.
__global__ __launch_bounds__(128, 2) void k_argmin(
        const float* __restrict__ x, const _Float16* __restrict__ ef,
        const float* __restrict__ hn, int* __restrict__ idx_out,
        int* __restrict__ flag_cnt, int* __restrict__ flagged) {
    __shared__ float mm1[2][64];
    __shared__ float mm2[2][64];
    __shared__ int   mbi[2][64];
    const int tid = threadIdx.x;
    const int l = tid & 63, w = tid >> 6;     // 2 waves
    const int lr = l & 15, lg = l >> 4;
    const int r0 = blockIdx.x * 64;           // 64 rows per block (both waves)
    const int wofs = w * (KC / 2);            // code-half per wave

    // A fragments: 64 rows as f16 (4 row-groups x 4 k-tiles), in registers
    f16x8 a[4][4];
    #pragma unroll
    for (int i = 0; i < 4; ++i) {
        const float* xr = x + (size_t)(r0 + i * 16 + lr) * DIM + lg * 8;
        #pragma unroll
        for (int kt = 0; kt < 4; ++kt) {
            float4 v0 = *(const float4*)(xr + kt * 32);
            float4 v1 = *(const float4*)(xr + kt * 32 + 4);
            f16x8 av = { (_Float16)v0.x, (_Float16)v0.y, (_Float16)v0.z, (_Float16)v0.w,
                         (_Float16)v1.x, (_Float16)v1.y, (_Float16)v1.z, (_Float16)v1.w };
            a[i][kt] = av;
        }
    }

    const _Float16* bb = ef + (size_t)(wofs + lr) * DIM + lg * 8;
    const float* hb = hn + wofs + lr;

    float m1[4][4], m2[4][4]; int bi[4][4];
    #pragma unroll
    for (int i = 0; i < 4; ++i)
        #pragma unroll
        for (int rg = 0; rg < 4; ++rg) { m1[i][rg] = -3e38f; m2[i][rg] = -3e38f; bi[i][rg] = 0; }

    #define LOADB(t, b)                                                          \
        {                                                                        \
            const _Float16* p_ = bb + (size_t)(t) * 32 * DIM;                    \
            _Pragma("unroll")                                                    \
            for (int c_ = 0; c_ < 2; ++c_)                                       \
                _Pragma("unroll")                                                \
                for (int kt_ = 0; kt_ < 4; ++kt_)                                \
                    b[c_][kt_] = *(const f16x8*)(p_ + c_ * 16 * DIM + kt_ * 32); \
        }

    #define COMPUTE(t, b)                                                        \
        {                                                                        \
            const float h0_ = hb[(t) * 32], h1_ = hb[(t) * 32 + 16];             \
            f32x4 acc[4][2] = {};                                                \
            _Pragma("unroll")                                                    \
            for (int kt_ = 0; kt_ < 4; ++kt_)                                    \
                _Pragma("unroll")                                                \
                for (int i_ = 0; i_ < 4; ++i_) {                                 \
                    acc[i_][0] = __builtin_amdgcn_mfma_f32_16x16x32_f16(         \
                        a[i_][kt_], b[0][kt_], acc[i_][0], 0, 0, 0);             \
                    acc[i_][1] = __builtin_amdgcn_mfma_f32_16x16x32_f16(         \
                        a[i_][kt_], b[1][kt_], acc[i_][1], 0, 0, 0);             \
                }                                                                \
            const int c0_ = wofs + (t) * 32 + lr, c1_ = c0_ + 16;                \
            _Pragma("unroll")                                                    \
            for (int i_ = 0; i_ < 4; ++i_)                                       \
                _Pragma("unroll")                                                \
                for (int rg_ = 0; rg_ < 4; ++rg_) {                              \
                    float v0_ = acc[i_][0][rg_] - h0_;                           \
                    bool g0_ = v0_ > m1[i_][rg_];                                \
                    m2[i_][rg_] = fmaxf(fminf(v0_, m1[i_][rg_]), m2[i_][rg_]);   \
                    m1[i_][rg_] = fmaxf(m1[i_][rg_], v0_);                       \
                    bi[i_][rg_] = g0_ ? c0_ : bi[i_][rg_];                       \
                    float v1_ = acc[i_][1][rg_] - h1_;                           \
                    bool g1_ = v1_ > m1[i_][rg_];                                \
                    m2[i_][rg_] = fmaxf(fminf(v1_, m1[i_][rg_]), m2[i_][rg_]);   \
                    m1[i_][rg_] = fmaxf(m1[i_][rg_], v1_);                       \
                    bi[i_][rg_] = g1_ ? c1_ : bi[i_][rg_];                       \
                }                                                                \
        }

    // 16 tiles of 32 codes; explicit register double-buffer (b0/b1)
    f16x8 b0[2][4], b1[2][4];
    LOADB(0, b0)
    for (int t = 0; t < KC / 64; t += 2) {    // t in {0,2,..,14}, tiles t,t+1
        LOADB(t + 1, b1)
        COMPUTE(t, b0)
        if (t + 2 < KC / 64) LOADB(t + 2, b0)
        COMPUTE(t + 1, b1)
    }
    #undef LOADB
    #undef COMPUTE

    // merge top-2 across the 16 lanes sharing each row
    #pragma unroll
    for (int i = 0; i < 4; ++i)
        #pragma unroll
        for (int rg = 0; rg < 4; ++rg) {
            float a1 = m1[i][rg], a2 = m2[i][rg]; int ai = bi[i][rg];
            #pragma unroll
            for (int mask = 1; mask < 16; mask <<= 1) {
                float o1 = __shfl_xor(a1, mask);
                float o2 = __shfl_xor(a2, mask);
                int   oi = __shfl_xor(ai, mask);
                float nm2 = fmaxf(fmaxf(a2, o2), fminf(a1, o1));
                if (o1 > a1 || (o1 == a1 && oi < ai)) { a1 = o1; ai = oi; }
                a2 = nm2;
            }
            if (lr == 0) {
                int rl = i * 16 + lg * 4 + rg;
                mm1[w][rl] = a1; mm2[w][rl] = a2; mbi[w][rl] = ai;
            }
        }
    __syncthreads();

    // cross-wave merge (disjoint code halves; strict > keeps smaller index)
    if (tid < 64) {
        float p1 = mm1[0][tid], p2 = mm2[0][tid]; int pi = mbi[0][tid];
        float q1 = mm1[1][tid], q2 = mm2[1][tid]; int qi = mbi[1][tid];
        float a1, a2; int ai;
        if (q1 > p1) { a1 = q1; ai = qi; a2 = fmaxf(p1, q2); }
        else         { a1 = p1; ai = pi; a2 = fmaxf(p2, q1); }
        int row = r0 + tid;
        idx_out[row] = ai;
        if (a1 - a2 < GAP_THR) {              // near-tie: exact recheck later
            int p = atomicAdd(flag_cnt, 1);
            flagged[p] = row;
        }
    }
}

// ---- exact fp64 recheck over transposed codebook: block per flagged row ----
__global__ __launch_bounds__(256) void k_recheck(
        const float* __restrict__ x, const float* __restrict__ embT,
        const double* __restrict__ hn64, int* __restrict__ idx_out,
        const int* __restrict__ flag_cnt, const int* __restrict__ flagged) {
    __shared__ double xd[DIM];
    __shared__ double wv[4];
    __shared__ int    wk[4];
    const int tid = threadIdx.x;
    const int cnt = flag_cnt[0];
    for (int f = blockIdx.x; f < cnt; f += gridDim.x) {
        const int row = flagged[f];
        __syncthreads();                       // xd/wv reuse guard
        if (tid < DIM) xd[tid] = (double)x[(size_t)row * DIM + tid];
        __syncthreads();
        const float* tp = embT + tid;
        double s0 = 0.0, s1 = 0.0, s2 = 0.0, s3 = 0.0;
        #pragma unroll 4
        for (int j = 0; j < DIM; ++j) {
            const float* rp = tp + (size_t)j * KC;
            double xv = xd[j];
            s0 = fma((double)rp[0],   xv, s0);
            s1 = fma((double)rp[256], xv, s1);
            s2 = fma((double)rp[512], xv, s2);
            s3 = fma((double)rp[768], xv, s3);
        }
        double bv = s0 - hn64[tid];       int bk = tid;
        double v1 = s1 - hn64[tid + 256];
        if (v1 > bv) { bv = v1; bk = tid + 256; }
        double v2 = s2 - hn64[tid + 512];
        if (v2 > bv) { bv = v2; bk = tid + 512; }
        double v3 = s3 - hn64[tid + 768];
        if (v3 > bv) { bv = v3; bk = tid + 768; }
        #pragma unroll
        for (int m = 1; m < 64; m <<= 1) {
            double ov = __shfl_xor(bv, m);
            int    ok = __shfl_xor(bk, m);
            if (ov > bv || (ov == bv && ok < bk)) { bv = ov; bk = ok; }
        }
        const int w = tid >> 6;
        if ((tid & 63) == 0) { wv[w] = bv; wk[w] = bk; }
        __syncthreads();
        if (tid == 0) {
            double fv = wv[0]; int fk = wk[0];
            #pragma unroll
            for (int i = 1; i < 4; ++i)
                if (wv[i] > fv || (wv[i] == fv && wk[i] < fk)) { fv = wv[i]; fk = wk[i]; }
            idx_out[row] = fk;
        }
    }
}

// ---- fused: z+codes+diff partials (blocks 0..2047), histogram (2048..2111),
// finalize (last-done block computes diff mean + perplexity) ----
__global__ __launch_bounds__(256) void k_out(
        const float* __restrict__ x, const float* __restrict__ emb,
        const int* __restrict__ idx, float* __restrict__ out,
        float* __restrict__ part, unsigned* __restrict__ ghist,
        unsigned* __restrict__ done) {
    __shared__ unsigned hist[KC];
    __shared__ double sh[256];
    __shared__ float red[4];
    __shared__ unsigned rank_sh;
    const int bid = blockIdx.x, tid = threadIdx.x;

    if (bid < NB_OUT) {
        float d = 0.f;
        #pragma unroll
        for (int it = 0; it < 4; ++it) {
            int i = bid * 256 + tid + it * (NB_OUT * 256);
            int e0 = i * 4;
            int row = e0 >> 7;
            int col = e0 & (DIM - 1);
            int k = idx[row];
            float4 xv = *(const float4*)(x + e0);
            float4 qv = *(const float4*)(emb + (size_t)k * DIM + col);
            float dx = qv.x - xv.x, dy = qv.y - xv.y, dz = qv.z - xv.z, dw = qv.w - xv.w;
            float4 z;
            z.x = xv.x + dx; z.y = xv.y + dy; z.z = xv.z + dz; z.w = xv.w + dw;
            *(float4*)(out + OUT_Z + e0) = z;
            d += dx*dx + dy*dy + dz*dz + dw*dw;
            if (col == 0) out[OUT_CODES + row] = (float)k;
        }
        for (int off = 32; off; off >>= 1) d += __shfl_down(d, off);
        int lane = tid & 63, w = tid >> 6;
        if (lane == 0) red[w] = d;
        __syncthreads();
        if (tid == 0)  // device-coherent store (read later via atomic)
            atomicExch(&part[bid], (red[0] + red[1]) + (red[2] + red[3]));
    } else {
        const int hb = bid - NB_OUT;          // 0..63
        #pragma unroll
        for (int i = 0; i < KC / 256; ++i) hist[i * 256 + tid] = 0u;
        __syncthreads();
        const int base = hb * (NROWS / NB_HIST);
        #pragma unroll
        for (int it = 0; it < NROWS / NB_HIST / 256; ++it)
            atomicAdd(&hist[idx[base + it * 256 + tid]], 1u);
        __syncthreads();
        #pragma unroll
        for (int i = 0; i < KC / 256; ++i) {
            unsigned c = hist[i * 256 + tid];
            if (c) atomicAdd(&ghist[i * 256 + tid], c);
        }
    }
    __syncthreads();
    if (tid == 0) { __threadfence(); rank_sh = atomicAdd(done, 1u); }
    __syncthreads();
    if (rank_sh != NB_OUT + NB_HIST - 1) return;

    // last block: diff mean + perplexity (coherent atomic reads)
    double s = 0.0;
    #pragma unroll
    for (int it = 0; it < NB_OUT / 256; ++it)
        s += (double)atomicAdd(&part[it * 256 + tid], 0.0f);
    sh[tid] = s;
    __syncthreads();
    for (int st = 128; st; st >>= 1) {
        if (tid < st) sh[tid] += sh[tid + st];
        __syncthreads();
    }
    double diff = sh[0] * (1.0 / (double)XEL);
    double lp = 0.0;
    #pragma unroll
    for (int i = 0; i < KC / 256; ++i) {
        unsigned c = atomicAdd(&ghist[i * 256 + tid], 0u);
        double p = (double)c * (1.0 / (double)NROWS);
        lp += p * log(p + 1e-5);
    }
    __syncthreads();
    sh[tid] = lp;
    __syncthreads();
    for (int st = 128; st; st >>= 1) {
        if (tid < st) sh[tid] += sh[tid + st];
        __syncthreads();
    }
    if (tid == 0) {
        out[OUT_DIFF] = (float)diff;
        out[OUT_PPL]  = (float)(-sh[0]);
    }
}

extern "C" void kernel_launch(void* const* d_in, const int* in_sizes, int n_in,
                              void* d_out, int out_size, void* d_ws, size_t ws_size,
                              hipStream_t stream) {
    const float* x   = (const float*)d_in[0];
    const float* emb = (const float*)d_in[1];
    float* out = (float*)d_out;
    int*   wi  = (int*)d_ws;
    float* wf  = (float*)d_ws;
    unsigned* wu = (unsigned*)d_ws;
    double* hn64 = (double*)((float*)d_ws + WS_HN64);
    _Float16* ef = (_Float16*)((float*)d_ws + WS_EF);
    float* embT  = (float*)d_ws + WS_ET;

    k_prep<<<KC / 8, 256, 0, stream>>>(emb, ef, embT, wf + WS_HN, hn64, wu + WS_CNT);
    k_argmin<<<NROWS / 64, 128, 0, stream>>>(x, ef, wf + WS_HN,
                                             wi + WS_IDX, wi + WS_CNT, wi + WS_FLAG);
    k_recheck<<<1024, 256, 0, stream>>>(x, embT, hn64, wi + WS_IDX,
                                        wi + WS_CNT, wi + WS_FLAG);
    k_out<<<NB_OUT + NB_HIST, 256, 0, stream>>>(x, emb, wi + WS_IDX, out,
                                                wf + WS_PART, wu + WS_HIST,
                                                wu + WS_DONE);
}

// Round 12
// 98.973 us; speedup vs baseline: 1.6194x; 1.6194x over previous
//
#include <hip/hip_runtime.h>
#include <math.h>

constexpr int DIM   = 128;
constexpr int KC    = 1024;
constexpr int NROWS = 65536;                 // 16384*512/128
constexpr int XEL   = NROWS * DIM;           // 8388608

// output layout (floats)
constexpr int OUT_Z     = 0;
constexpr int OUT_DIFF  = XEL;               // 8388608
constexpr int OUT_CODES = XEL + 1;           // 8388609
constexpr int OUT_PPL   = XEL + 1 + NROWS;   // 8454145

// ws layout (4-byte units)
constexpr int WS_IDX  = 0;                   // int[NROWS]
constexpr int WS_FLAG = NROWS;               // int[NROWS]
constexpr int WS_CNT  = 2 * NROWS;           // int   (zeroed by k_prep)
constexpr int WS_DONE = WS_CNT + 1;          // u32   (zeroed by k_prep)
constexpr int WS_HIST = WS_DONE + 1;         // u32[KC] (zeroed by k_prep)
constexpr int WS_HN   = WS_HIST + KC;        // float[KC]
constexpr int WS_PART = WS_HN + KC;          // float[2048] diff partials
constexpr int WS_HN64 = WS_PART + 2048;      // double[KC] (2048 words, 8B-aligned)
constexpr int WS_EF   = WS_HN64 + 2 * KC;    // _Float16[KC*DIM] = 65536 words
constexpr int WS_ET   = WS_EF + (KC * DIM / 2); // float[DIM*KC] transposed = 131072 words

constexpr int NB_OUT = 2048;                 // k_output blocks

// single-pass f16 score error std ~5e-3; 0.06 = >10 sigma pairwise margin
constexpr float GAP_THR = 0.06f;

typedef _Float16 f16x8 __attribute__((ext_vector_type(8)));
typedef _Float16 f16x4 __attribute__((ext_vector_type(4)));
typedef float f32x4 __attribute__((ext_vector_type(4)));

// ---- emb -> f16 + transposed fp32 + fp64 half-norms; zero counters/hist ----
__global__ __launch_bounds__(256) void k_prep(
        const float* __restrict__ emb, _Float16* __restrict__ ef,
        float* __restrict__ embT, float* __restrict__ hn,
        double* __restrict__ hn64, unsigned* __restrict__ zbase) {
    __shared__ float ldsT[DIM][9];            // 8 codes transposed, +1 pad col
    const int tid = threadIdx.x;
    if (blockIdx.x == 0)
        for (int i = tid; i < 2 + KC; i += 256) zbase[i] = 0u;   // CNT, DONE, HIST
    const int cc   = tid >> 5;                // 0..7 code within block
    const int code = blockIdx.x * 8 + cc;
    const int jq   = tid & 31;                // float4 index
    float4 v = *(const float4*)(emb + (size_t)code * DIM + jq * 4);
    f16x4 h = { (_Float16)v.x, (_Float16)v.y, (_Float16)v.z, (_Float16)v.w };
    *(f16x4*)(ef + (size_t)code * DIM + jq * 4) = h;
    ldsT[jq * 4 + 0][cc] = v.x;
    ldsT[jq * 4 + 1][cc] = v.y;
    ldsT[jq * 4 + 2][cc] = v.z;
    ldsT[jq * 4 + 3][cc] = v.w;
    double s = (double)v.x * v.x + (double)v.y * v.y
             + (double)v.z * v.z + (double)v.w * v.w;
    #pragma unroll
    for (int m = 1; m < 32; m <<= 1) s += __shfl_xor(s, m);
    if (jq == 0) {
        hn[code]   = (float)(0.5 * s);
        hn64[code] = 0.5 * s;
    }
    __syncthreads();
    #pragma unroll
    for (int i = 0; i < 4; ++i) {
        int idx = i * 256 + tid;
        int j = idx >> 3, c = idx & 7;
        embT[(size_t)j * KC + blockIdx.x * 8 + c] = ldsT[j][c];
    }
}

// ---- main: f16 MFMA scores, TRIPLE-buffered LDS via global_load_lds ----
// 4 waves x 32 rows; 64-code tiles; one barrier/tile; counted vmcnt(4) so
// each tile's loads get TWO compute phases to land (T4, m218).
__global__ __launch_bounds__(256, 2) void k_argmin(
        const float* __restrict__ x, const _Float16* __restrict__ ef,
        const float* __restrict__ hn, int* __restrict__ idx_out,
        int* __restrict__ flag_cnt, int* __restrict__ flagged) {
    __shared__ _Float16 bt[3][8192];          // 3 x 16KB rotating buffers
    __shared__ float hn_lds[KC];
    const int tid = threadIdx.x;
    const int l = tid & 63, w = tid >> 6;     // 4 waves
    const int lr = l & 15, lg = l >> 4;
    const int r0 = blockIdx.x * 128 + w * 32; // 32 rows per wave

    // stage hn into LDS once (plain stores; first barrier covers them)
    #pragma unroll
    for (int i = 0; i < 4; ++i) hn_lds[i * 256 + tid] = hn[i * 256 + tid];

    // A fragments: 32 rows as f16 (2 row-groups x 4 k-tiles), in registers
    f16x8 a[2][4];
    #pragma unroll
    for (int i = 0; i < 2; ++i) {
        const float* xr = x + (size_t)(r0 + i * 16 + lr) * DIM + lg * 8;
        #pragma unroll
        for (int kt = 0; kt < 4; ++kt) {
            float4 v0 = *(const float4*)(xr + kt * 32);
            float4 v1 = *(const float4*)(xr + kt * 32 + 4);
            f16x8 av = { (_Float16)v0.x, (_Float16)v0.y, (_Float16)v0.z, (_Float16)v0.w,
                         (_Float16)v1.x, (_Float16)v1.y, (_Float16)v1.z, (_Float16)v1.w };
            a[i][kt] = av;
        }
    }

    // wave w owns chunks q=w*4+i -> codes c=w (16 codes), dims kt=i.
    // LDS dest: wave-uniform chunk base; HW writes base + lane*16B.
    // Global src per lane: code (w*16+lr), dims i*32 + lg*8.
    const _Float16* gsrc[4];
    #pragma unroll
    for (int i = 0; i < 4; ++i)
        gsrc[i] = ef + (size_t)(w * 16 + lr) * DIM + i * 32 + lg * 8;

    #define ISSUE_TILE(t, buf)                                                   \
        {                                                                        \
            _Pragma("unroll")                                                    \
            for (int i_ = 0; i_ < 4; ++i_) {                                     \
                const _Float16* g_ = gsrc[i_] + (size_t)(t) * 64 * DIM;          \
                __builtin_amdgcn_global_load_lds(                                \
                    (const __attribute__((address_space(1))) unsigned*)g_,       \
                    (__attribute__((address_space(3))) unsigned*)                \
                        &bt[buf][(w * 4 + i_) * 512],                            \
                    16, 0, 0);                                                   \
            }                                                                    \
        }

    ISSUE_TILE(0, 0)
    ISSUE_TILE(1, 1)
    asm volatile("s_waitcnt vmcnt(4)" ::: "memory");  // tile 0 landed; tile 1 in flight
    __syncthreads();                          // tile 0 + hn_lds visible

    float m1[2][4], m2[2][4]; int bi[2][4];
    #pragma unroll
    for (int i = 0; i < 2; ++i)
        #pragma unroll
        for (int rg = 0; rg < 4; ++rg) { m1[i][rg] = -3e38f; m2[i][rg] = -3e38f; bi[i][rg] = 0; }

    constexpr int NT = KC / 64;               // 16 tiles
    for (int t = 0; t < NT; ++t) {
        const int buf = t % 3;
        if (t + 2 < NT) ISSUE_TILE(t + 2, (t + 2) % 3)
        float hnv[4];
        #pragma unroll
        for (int c = 0; c < 4; ++c) hnv[c] = hn_lds[t * 64 + c * 16 + lr];
        f32x4 acc[2][4] = {};                 // 8 independent 4-deep MFMA chains
        __builtin_amdgcn_s_setprio(1);
        #pragma unroll
        for (int kt = 0; kt < 4; ++kt) {
            f16x8 b[4];
            #pragma unroll
            for (int c = 0; c < 4; ++c)
                b[c] = *(const f16x8*)(&bt[buf][(c * 4 + kt) * 512 + l * 8]);
            #pragma unroll
            for (int i = 0; i < 2; ++i)
                #pragma unroll
                for (int c = 0; c < 4; ++c)
                    acc[i][c] = __builtin_amdgcn_mfma_f32_16x16x32_f16(a[i][kt], b[c], acc[i][c], 0, 0, 0);
        }
        __builtin_amdgcn_s_setprio(0);
        #pragma unroll
        for (int i = 0; i < 2; ++i)
            #pragma unroll
            for (int c = 0; c < 4; ++c) {
                const int cc = t * 64 + c * 16 + lr;
                #pragma unroll
                for (int rg = 0; rg < 4; ++rg) {
                    float v = acc[i][c][rg] - hnv[c];
                    bool g = v > m1[i][rg];
                    // m1>=m2 invariant -> median(v,m1,m2) == new second-best
                    m2[i][rg] = fmaxf(fminf(v, m1[i][rg]), m2[i][rg]);
                    m1[i][rg] = fmaxf(m1[i][rg], v);
                    bi[i][rg] = g ? cc : bi[i][rg];
                }
            }
        // tile t+1's loads (issued at t-1) done; t+2's may stay in flight
        if (t + 2 < NT) asm volatile("s_waitcnt vmcnt(4)" ::: "memory");
        else            asm volatile("s_waitcnt vmcnt(0)" ::: "memory");
        __syncthreads();                      // all waves done with bt[buf]
    }
    #undef ISSUE_TILE

    // merge top-2 across the 16 lanes sharing each row
    #pragma unroll
    for (int i = 0; i < 2; ++i)
        #pragma unroll
        for (int rg = 0; rg < 4; ++rg) {
            float a1 = m1[i][rg], a2 = m2[i][rg]; int ai = bi[i][rg];
            #pragma unroll
            for (int mask = 1; mask < 16; mask <<= 1) {
                float o1 = __shfl_xor(a1, mask);
                float o2 = __shfl_xor(a2, mask);
                int   oi = __shfl_xor(ai, mask);
                float nm2 = fmaxf(fmaxf(a2, o2), fminf(a1, o1));
                if (o1 > a1 || (o1 == a1 && oi < ai)) { a1 = o1; ai = oi; }
                a2 = nm2;
            }
            if (lr == 0) {
                int row = r0 + i * 16 + lg * 4 + rg;
                idx_out[row] = ai;
                if (a1 - a2 < GAP_THR) {      // near-tie: exact recheck later
                    int p = atomicAdd(flag_cnt, 1);
                    flagged[p] = row;
                }
            }
        }
}

// ---- exact fp64 recheck over transposed codebook: block per flagged row ----
__global__ __launch_bounds__(256) void k_recheck(
        const float* __restrict__ x, const float* __restrict__ embT,
        const double* __restrict__ hn64, int* __restrict__ idx_out,
        const int* __restrict__ flag_cnt, const int* __restrict__ flagged) {
    __shared__ double xd[DIM];
    __shared__ double wv[4];
    __shared__ int    wk[4];
    const int tid = threadIdx.x;
    const int cnt = flag_cnt[0];
    for (int f = blockIdx.x; f < cnt; f += gridDim.x) {
        const int row = flagged[f];
        __syncthreads();                       // xd/wv reuse guard
        if (tid < DIM) xd[tid] = (double)x[(size_t)row * DIM + tid];
        __syncthreads();
        const float* tp = embT + tid;
        double s0 = 0.0, s1 = 0.0, s2 = 0.0, s3 = 0.0;
        #pragma unroll 4
        for (int j = 0; j < DIM; ++j) {
            const float* rp = tp + (size_t)j * KC;
            double xv = xd[j];
            s0 = fma((double)rp[0],   xv, s0);
            s1 = fma((double)rp[256], xv, s1);
            s2 = fma((double)rp[512], xv, s2);
            s3 = fma((double)rp[768], xv, s3);
        }
        double bv = s0 - hn64[tid];       int bk = tid;
        double v1 = s1 - hn64[tid + 256];
        if (v1 > bv) { bv = v1; bk = tid + 256; }
        double v2 = s2 - hn64[tid + 512];
        if (v2 > bv) { bv = v2; bk = tid + 512; }
        double v3 = s3 - hn64[tid + 768];
        if (v3 > bv) { bv = v3; bk = tid + 768; }
        #pragma unroll
        for (int m = 1; m < 64; m <<= 1) {
            double ov = __shfl_xor(bv, m);
            int    ok = __shfl_xor(bk, m);
            if (ov > bv || (ov == bv && ok < bk)) { bv = ov; bk = ok; }
        }
        const int w = tid >> 6;
        if ((tid & 63) == 0) { wv[w] = bv; wk[w] = bk; }
        __syncthreads();
        if (tid == 0) {
            double fv = wv[0]; int fk = wk[0];
            #pragma unroll
            for (int i = 1; i < 4; ++i)
                if (wv[i] > fv || (wv[i] == fv && wk[i] < fk)) { fv = wv[i]; fk = wk[i]; }
            idx_out[row] = fk;
        }
    }
}

// ---- z, codes, diff partials (no global atomics) ----
__global__ __launch_bounds__(256) void k_output(
        const float* __restrict__ x, const float* __restrict__ emb,
        const int* __restrict__ idx, float* __restrict__ out,
        float* __restrict__ part) {
    const int tid = threadIdx.x;
    float d = 0.f;
    #pragma unroll
    for (int it = 0; it < 4; ++it) {
        int i = blockIdx.x * 256 + tid + it * (NB_OUT * 256);
        int e0 = i * 4;
        int row = e0 >> 7;
        int col = e0 & (DIM - 1);
        int k = idx[row];
        float4 xv = *(const float4*)(x + e0);
        float4 qv = *(const float4*)(emb + (size_t)k * DIM + col);
        float dx = qv.x - xv.x, dy = qv.y - xv.y, dz = qv.z - xv.z, dw = qv.w - xv.w;
        float4 z;
        z.x = xv.x + dx; z.y = xv.y + dy; z.z = xv.z + dz; z.w = xv.w + dw;
        *(float4*)(out + OUT_Z + e0) = z;
        d += dx*dx + dy*dy + dz*dz + dw*dw;
        if (col == 0) out[OUT_CODES + row] = (float)k;
    }
    for (int off = 32; off; off >>= 1) d += __shfl_down(d, off);
    __shared__ float red[4];
    int lane = tid & 63, w = tid >> 6;
    if (lane == 0) red[w] = d;
    __syncthreads();
    if (tid == 0) part[blockIdx.x] = (red[0] + red[1]) + (red[2] + red[3]);
}

// ---- histogram (64 blocks) + finalize in last-done block ----
__global__ __launch_bounds__(256) void k_hist(
        const int* __restrict__ idx, unsigned* __restrict__ ghist,
        const float* __restrict__ part, unsigned* __restrict__ done,
        float* __restrict__ out) {
    __shared__ unsigned hist[KC];
    __shared__ double sh[256];
    __shared__ unsigned rank_sh;
    const int tid = threadIdx.x;
    #pragma unroll
    for (int i = 0; i < KC / 256; ++i) hist[i * 256 + tid] = 0u;
    __syncthreads();
    const int base = blockIdx.x * (NROWS / 64);
    #pragma unroll
    for (int it = 0; it < NROWS / 64 / 256; ++it)
        atomicAdd(&hist[idx[base + it * 256 + tid]], 1u);
    __syncthreads();
    #pragma unroll
    for (int i = 0; i < KC / 256; ++i) {
        unsigned c = hist[i * 256 + tid];
        if (c) atomicAdd(&ghist[i * 256 + tid], c);
    }
    __syncthreads();                          // all this block's merges complete
    if (tid == 0) { __threadfence(); rank_sh = atomicAdd(done, 1u); }
    __syncthreads();
    if (rank_sh != 63) return;
    // last block: diff mean + perplexity
    double s = 0.0;
    #pragma unroll
    for (int it = 0; it < 2048 / 256; ++it) s += (double)part[it * 256 + tid];
    sh[tid] = s;
    __syncthreads();
    for (int st = 128; st; st >>= 1) {
        if (tid < st) sh[tid] += sh[tid + st];
        __syncthreads();
    }
    double diff = sh[0] * (1.0 / (double)XEL);
    double lp = 0.0;
    #pragma unroll
    for (int i = 0; i < KC / 256; ++i) {
        unsigned c = atomicAdd(&ghist[i * 256 + tid], 0u);   // coherent read
        double p = (double)c * (1.0 / (double)NROWS);
        lp += p * log(p + 1e-5);
    }
    __syncthreads();
    sh[tid] = lp;
    __syncthreads();
    for (int st = 128; st; st >>= 1) {
        if (tid < st) sh[tid] += sh[tid + st];
        __syncthreads();
    }
    if (tid == 0) {
        out[OUT_DIFF] = (float)diff;
        out[OUT_PPL]  = (float)(-sh[0]);
    }
}

extern "C" void kernel_launch(void* const* d_in, const int* in_sizes, int n_in,
                              void* d_out, int out_size, void* d_ws, size_t ws_size,
                              hipStream_t stream) {
    const float* x   = (const float*)d_in[0];
    const float* emb = (const float*)d_in[1];
    float* out = (float*)d_out;
    int*   wi  = (int*)d_ws;
    float* wf  = (float*)d_ws;
    unsigned* wu = (unsigned*)d_ws;
    double* hn64 = (double*)((float*)d_ws + WS_HN64);
    _Float16* ef = (_Float16*)((float*)d_ws + WS_EF);
    float* embT  = (float*)d_ws + WS_ET;

    k_prep<<<KC / 8, 256, 0, stream>>>(emb, ef, embT, wf + WS_HN, hn64, wu + WS_CNT);
    k_argmin<<<NROWS / 128, 256, 0, stream>>>(x, ef, wf + WS_HN,
                                              wi + WS_IDX, wi + WS_CNT, wi + WS_FLAG);
    k_recheck<<<1024, 256, 0, stream>>>(x, embT, hn64, wi + WS_IDX,
                                        wi + WS_CNT, wi + WS_FLAG);
    k_output<<<NB_OUT, 256, 0, stream>>>(x, emb, wi + WS_IDX, out, wf + WS_PART);
    k_hist<<<64, 256, 0, stream>>>(wi + WS_IDX, wu + WS_HIST, wf + WS_PART,
                                   wu + WS_DONE, out);
}